// Round 1
// baseline (150.580 us; speedup 1.0000x reference)
//
#include <hip/hip_runtime.h>
#include <math.h>

// MonotoneFeatureTransform: rational-quadratic spline per feature + batch standardize.
// B=131072, F=256, K=16. f32 in/out.

#define FEAT 256
#define KBINS 16
#define BATCH 131072
#define BOUNDF 5.0f
#define MIN_Df 1e-3f
#define MIN_BWf 1e-3f
#define MIN_BHf 1e-3f
#define EPSF 1e-8f

#define GRID1 512
#define ROWS (BATCH / GRID1) // 256 rows per block

// ws layout (float offsets). Total ~1.1 MB.
#define OFF_CW 0                    // [256][17] knot x positions
#define OFF_CH 4352                 // [256][17] knot y positions
#define OFF_D  8704                 // [256][17] derivatives at knots
#define OFF_MEAN 13056              // [256]
#define OFF_ISTD 13312              // [256]
#define OFF_PS 16384                // [GRID1][256] partial sums
#define OFF_PS2 (OFF_PS + GRID1*FEAT) // [GRID1][256] partial sumsq

__global__ __launch_bounds__(256) void k_params(const float* __restrict__ uw,
                                                const float* __restrict__ uh,
                                                const float* __restrict__ ud,
                                                float* __restrict__ ws) {
    int f = threadIdx.x;
    // ---- width knots (cw) ----
    {
        float u[KBINS];
#pragma unroll
        for (int j = 0; j < KBINS; j++) u[j] = uw[f * KBINS + j];
        float m = u[0];
#pragma unroll
        for (int j = 1; j < KBINS; j++) m = fmaxf(m, u[j]);
        float ssum = 0.f;
#pragma unroll
        for (int j = 0; j < KBINS; j++) { u[j] = expf(u[j] - m); ssum += u[j]; }
        float inv = 1.0f / ssum;
        float cum = 0.f;
        ws[OFF_CW + f * 17 + 0] = -BOUNDF;
#pragma unroll
        for (int j = 1; j < KBINS; j++) {
            float wj = MIN_BWf + (1.0f - MIN_BWf * (float)KBINS) * (u[j - 1] * inv);
            cum += wj;
            ws[OFF_CW + f * 17 + j] = 2.0f * BOUNDF * cum - BOUNDF;
        }
        ws[OFF_CW + f * 17 + KBINS] = BOUNDF;
    }
    // ---- height knots (ch) ----
    {
        float u[KBINS];
#pragma unroll
        for (int j = 0; j < KBINS; j++) u[j] = uh[f * KBINS + j];
        float m = u[0];
#pragma unroll
        for (int j = 1; j < KBINS; j++) m = fmaxf(m, u[j]);
        float ssum = 0.f;
#pragma unroll
        for (int j = 0; j < KBINS; j++) { u[j] = expf(u[j] - m); ssum += u[j]; }
        float inv = 1.0f / ssum;
        float cum = 0.f;
        ws[OFF_CH + f * 17 + 0] = -BOUNDF;
#pragma unroll
        for (int j = 1; j < KBINS; j++) {
            float wj = MIN_BHf + (1.0f - MIN_BHf * (float)KBINS) * (u[j - 1] * inv);
            cum += wj;
            ws[OFF_CH + f * 17 + j] = 2.0f * BOUNDF * cum - BOUNDF;
        }
        ws[OFF_CH + f * 17 + KBINS] = BOUNDF;
    }
    // ---- derivatives (d) : pad => softplus(log(expm1(1-MIN_D))) + MIN_D == 1.0 ----
    {
        ws[OFF_D + f * 17 + 0] = 1.0f;
        ws[OFF_D + f * 17 + KBINS] = 1.0f;
#pragma unroll
        for (int j = 1; j < KBINS; j++) {
            float v = ud[f * (KBINS - 1) + (j - 1)];
            float sp = fmaxf(v, 0.0f) + log1pf(expf(-fabsf(v))); // stable softplus
            ws[OFF_D + f * 17 + j] = MIN_Df + sp;
        }
    }
}

// Spline evaluation for one element; tables are per-feature slices in LDS.
__device__ __forceinline__ float eval_spline(float xv, float shift, float invsc,
                                             const float* __restrict__ cw_s,
                                             const float* __restrict__ ch_s,
                                             const float* __restrict__ d_s,
                                             const float knots[15]) {
    float xn = (xv - shift) * invsc;
    float xc = fminf(fmaxf(xn, -BOUNDF), BOUNDF);
    int idx = 0;
#pragma unroll
    for (int j = 0; j < 15; j++) idx += (xc >= knots[j]) ? 1 : 0;
    float cw0 = cw_s[idx], cw1 = cw_s[idx + 1];
    float ch0 = ch_s[idx], ch1 = ch_s[idx + 1];
    float d0 = d_s[idx],  d1 = d_s[idx + 1];
    float wbin = cw1 - cw0;
    float binv = __builtin_amdgcn_rcpf(wbin);
    float hbin = ch1 - ch0;
    float delta = hbin * binv;
    float theta = (xc - cw0) * binv;
    float th2 = theta * theta;
    float t1m = theta - th2;
    float numer = hbin * fmaf(delta, th2, d0 * t1m);
    float denom = fmaf(d0 + d1 - 2.0f * delta, t1m, delta);
    float s = fmaf(numer, __builtin_amdgcn_rcpf(denom), ch0);
    bool inside = (xn > -BOUNDF) && (xn < BOUNDF);
    return inside ? s : xn;
}

__global__ __launch_bounds__(256, 2) void k_pass1(const float* __restrict__ X,
                                                  const float* __restrict__ shiftp,
                                                  const float* __restrict__ scalep,
                                                  float* __restrict__ ws) {
    __shared__ float tab[13056]; // 52224 B: cw | ch | d, each [256][17]
    for (int i = threadIdx.x; i < 13056; i += 256) tab[i] = ws[i];
    __syncthreads();
    int f = threadIdx.x;
    const float* cw_s = tab + f * 17;
    const float* ch_s = tab + 4352 + f * 17;
    const float* d_s  = tab + 8704 + f * 17;
    float knots[15];
#pragma unroll
    for (int j = 0; j < 15; j++) knots[j] = cw_s[j + 1];
    float shift = shiftp[f];
    float invsc = 1.0f / scalep[f];
    float sum = 0.f, sumsq = 0.f;
    size_t base = (size_t)blockIdx.x * ROWS * FEAT + f;
#pragma unroll 4
    for (int r = 0; r < ROWS; r++) {
        float xv = X[base + (size_t)r * FEAT];
        float s = eval_spline(xv, shift, invsc, cw_s, ch_s, d_s, knots);
        sum += s;
        sumsq = fmaf(s, s, sumsq);
    }
    ws[OFF_PS + blockIdx.x * FEAT + f] = sum;
    ws[OFF_PS2 + blockIdx.x * FEAT + f] = sumsq;
}

__global__ __launch_bounds__(256) void k_reduce(float* __restrict__ ws) {
    int fB = blockIdx.x;
    int t = threadIdx.x;
    __shared__ float r1[256], r2[256];
    // GRID1=512 partials per feature -> each thread folds 2
    float s1 = ws[OFF_PS + t * FEAT + fB] + ws[OFF_PS + (t + 256) * FEAT + fB];
    float s2 = ws[OFF_PS2 + t * FEAT + fB] + ws[OFF_PS2 + (t + 256) * FEAT + fB];
    r1[t] = s1; r2[t] = s2;
    __syncthreads();
    for (int off = 128; off > 0; off >>= 1) {
        if (t < off) { r1[t] += r1[t + off]; r2[t] += r2[t + off]; }
        __syncthreads();
    }
    if (t == 0) {
        float mean = r1[0] * (1.0f / (float)BATCH);
        float var = r2[0] * (1.0f / (float)BATCH) - mean * mean;
        var = fmaxf(var, 0.0f);
        ws[OFF_MEAN + fB] = mean;
        ws[OFF_ISTD + fB] = 1.0f / sqrtf(var + EPSF);
    }
}

__global__ __launch_bounds__(256, 2) void k_pass2(const float* __restrict__ X,
                                                  const float* __restrict__ shiftp,
                                                  const float* __restrict__ scalep,
                                                  const float* __restrict__ ws,
                                                  float* __restrict__ Z) {
    __shared__ float tab[13056];
    for (int i = threadIdx.x; i < 13056; i += 256) tab[i] = ws[i];
    __syncthreads();
    int f = threadIdx.x;
    const float* cw_s = tab + f * 17;
    const float* ch_s = tab + 4352 + f * 17;
    const float* d_s  = tab + 8704 + f * 17;
    float knots[15];
#pragma unroll
    for (int j = 0; j < 15; j++) knots[j] = cw_s[j + 1];
    float shift = shiftp[f];
    float invsc = 1.0f / scalep[f];
    float mean = ws[OFF_MEAN + f];
    float istd = ws[OFF_ISTD + f];
    size_t base = (size_t)blockIdx.x * ROWS * FEAT + f;
#pragma unroll 4
    for (int r = 0; r < ROWS; r++) {
        float xv = X[base + (size_t)r * FEAT];
        float s = eval_spline(xv, shift, invsc, cw_s, ch_s, d_s, knots);
        Z[base + (size_t)r * FEAT] = (s - mean) * istd;
    }
}

extern "C" void kernel_launch(void* const* d_in, const int* in_sizes, int n_in,
                              void* d_out, int out_size, void* d_ws, size_t ws_size,
                              hipStream_t stream) {
    const float* x     = (const float*)d_in[0];
    const float* uw    = (const float*)d_in[1];
    const float* uh    = (const float*)d_in[2];
    const float* ud    = (const float*)d_in[3];
    const float* shift = (const float*)d_in[4];
    const float* scale = (const float*)d_in[5];
    float* out = (float*)d_out;
    float* ws  = (float*)d_ws; // needs ~1.12 MB

    k_params<<<1, 256, 0, stream>>>(uw, uh, ud, ws);
    k_pass1<<<GRID1, 256, 0, stream>>>(x, shift, scale, ws);
    k_reduce<<<FEAT, 256, 0, stream>>>(ws);
    k_pass2<<<GRID1, 256, 0, stream>>>(x, shift, scale, ws, out);
}

// Round 2
// 116.836 us; speedup vs baseline: 1.2888x; 1.2888x over previous
//
#include <hip/hip_runtime.h>
#include <math.h>

// MonotoneFeatureTransform: rational-quadratic spline per feature + batch standardize.
// B=131072, F=256, K=16. f32 in/out.

#define FEAT 256
#define KBINS 16
#define BATCH 131072
#define BOUNDF 5.0f
#define MIN_Df 1e-3f
#define MIN_BWf 1e-3f
#define MIN_BHf 1e-3f
#define EPSF 1e-8f

#define FT_TILES 4
#define FT 64                 // features per tile
#define RB 256                // row blocks
#define ROWS_PB (BATCH / RB)  // 512 rows per block
#define SLOTS 4               // row slots (waves) per block
#define ITERS (ROWS_PB / SLOTS) // 128 rows per thread

// ws layout (float offsets). Total ~683 KB.
#define OFF_P0   0                        // [256][17] float4: cw0*binv, binv, h*delta, h*d0
#define OFF_P1   17408                    // [256][17] float4: d0+d1-2delta, delta, ch0, pad
#define OFF_CW   34816                    // [256][17] knot x positions
#define OFF_MEAN 39168                    // [256]
#define OFF_ISTD 39424                    // [256]
#define OFF_PS   39680                    // [1024][64] partial sums
#define OFF_PS2  (OFF_PS + 1024 * 64)     // [1024][64] partial sumsq

__global__ __launch_bounds__(256) void k_params(const float* __restrict__ uw,
                                                const float* __restrict__ uh,
                                                const float* __restrict__ ud,
                                                float* __restrict__ ws) {
    int f = threadIdx.x;
    float cw[17], ch[17], dv[17];
    // ---- width knots ----
    {
        float u[KBINS];
#pragma unroll
        for (int j = 0; j < KBINS; j++) u[j] = uw[f * KBINS + j];
        float m = u[0];
#pragma unroll
        for (int j = 1; j < KBINS; j++) m = fmaxf(m, u[j]);
        float ssum = 0.f;
#pragma unroll
        for (int j = 0; j < KBINS; j++) { u[j] = expf(u[j] - m); ssum += u[j]; }
        float inv = 1.0f / ssum;
        float cum = 0.f;
        cw[0] = -BOUNDF;
#pragma unroll
        for (int j = 1; j < KBINS; j++) {
            float wj = MIN_BWf + (1.0f - MIN_BWf * (float)KBINS) * (u[j - 1] * inv);
            cum += wj;
            cw[j] = 2.0f * BOUNDF * cum - BOUNDF;
        }
        cw[KBINS] = BOUNDF;
    }
    // ---- height knots ----
    {
        float u[KBINS];
#pragma unroll
        for (int j = 0; j < KBINS; j++) u[j] = uh[f * KBINS + j];
        float m = u[0];
#pragma unroll
        for (int j = 1; j < KBINS; j++) m = fmaxf(m, u[j]);
        float ssum = 0.f;
#pragma unroll
        for (int j = 0; j < KBINS; j++) { u[j] = expf(u[j] - m); ssum += u[j]; }
        float inv = 1.0f / ssum;
        float cum = 0.f;
        ch[0] = -BOUNDF;
#pragma unroll
        for (int j = 1; j < KBINS; j++) {
            float wj = MIN_BHf + (1.0f - MIN_BHf * (float)KBINS) * (u[j - 1] * inv);
            cum += wj;
            ch[j] = 2.0f * BOUNDF * cum - BOUNDF;
        }
        ch[KBINS] = BOUNDF;
    }
    // ---- derivatives: boundary pads give exactly 1.0 ----
    {
        dv[0] = 1.0f;
        dv[KBINS] = 1.0f;
#pragma unroll
        for (int j = 1; j < KBINS; j++) {
            float v = ud[f * (KBINS - 1) + (j - 1)];
            float sp = fmaxf(v, 0.0f) + log1pf(expf(-fabsf(v))); // stable softplus
            dv[j] = MIN_Df + sp;
        }
    }
    // ---- store knot row ----
#pragma unroll
    for (int j = 0; j <= KBINS; j++) ws[OFF_CW + f * 17 + j] = cw[j];
    // ---- packed per-bin params ----
    float4* P0g = (float4*)(ws + OFF_P0);
    float4* P1g = (float4*)(ws + OFF_P1);
#pragma unroll
    for (int i = 0; i < KBINS; i++) {
        float w = cw[i + 1] - cw[i];
        float binv = 1.0f / w;
        float hb = ch[i + 1] - ch[i];
        float delta = hb * binv;
        float4 p0, p1;
        p0.x = cw[i] * binv;      // cw0*binv
        p0.y = binv;
        p0.z = hb * delta;        // h*delta
        p0.w = hb * dv[i];        // h*d0
        p1.x = dv[i] + dv[i + 1] - 2.0f * delta; // dsum
        p1.y = delta;
        p1.z = ch[i];
        p1.w = 0.0f;
        P0g[f * 17 + i] = p0;
        P1g[f * 17 + i] = p1;
    }
}

__device__ __forceinline__ float eval_rq(float xv, float a, float nb,
                                         const float4* __restrict__ sP0,
                                         const float4* __restrict__ sP1,
                                         const float kn[15], int l17) {
    float xn = fmaf(xv, a, nb);
    float xc = fminf(fmaxf(xn, -BOUNDF), BOUNDF);
    int idx = 0;
#pragma unroll
    for (int j = 0; j < 15; j++) idx += (xc >= kn[j]) ? 1 : 0;
    int o = l17 + idx;
    float4 p0 = sP0[o];
    float4 p1 = sP1[o];
    float th = fmaf(xc, p0.y, -p0.x);
    float th2 = th * th;
    float t1m = th - th2;
    float numer = fmaf(p0.z, th2, p0.w * t1m);
    float denom = fmaf(p1.x, t1m, p1.y);
    float s = fmaf(numer, __builtin_amdgcn_rcpf(denom), p1.z);
    return (fabsf(xn) < BOUNDF) ? s : xn;
}

__global__ __launch_bounds__(256, 4) void k_pass1(const float* __restrict__ X,
                                                  const float* __restrict__ shiftp,
                                                  const float* __restrict__ scalep,
                                                  float* __restrict__ ws) {
    __shared__ float4 sP0[FT * 17];
    __shared__ float4 sP1[FT * 17];
    __shared__ float red[2][SLOTS][FT];
    int t = threadIdx.x;
    int rb = blockIdx.x, ft = blockIdx.y;
    const float4* P0g = (const float4*)(ws + OFF_P0) + ft * FT * 17;
    const float4* P1g = (const float4*)(ws + OFF_P1) + ft * FT * 17;
    for (int i = t; i < FT * 17; i += 256) { sP0[i] = P0g[i]; sP1[i] = P1g[i]; }
    int l = t & 63, slot = t >> 6;
    int f = ft * FT + l;
    float kn[15];
#pragma unroll
    for (int j = 0; j < 15; j++) kn[j] = ws[OFF_CW + f * 17 + 1 + j];
    float a = 1.0f / scalep[f];
    float nb = -shiftp[f] * a;
    int l17 = l * 17;
    __syncthreads();
    const float* Xp = X + (size_t)(rb * ROWS_PB + slot) * FEAT + f;
    float sum = 0.f, sumsq = 0.f;
    for (int r = 0; r < ITERS; r += 4) {
        float x0 = Xp[0 * SLOTS * FEAT];
        float x1 = Xp[1 * SLOTS * FEAT];
        float x2 = Xp[2 * SLOTS * FEAT];
        float x3 = Xp[3 * SLOTS * FEAT];
        Xp += 4 * SLOTS * FEAT;
        float s0 = eval_rq(x0, a, nb, sP0, sP1, kn, l17);
        float s1 = eval_rq(x1, a, nb, sP0, sP1, kn, l17);
        float s2 = eval_rq(x2, a, nb, sP0, sP1, kn, l17);
        float s3 = eval_rq(x3, a, nb, sP0, sP1, kn, l17);
        sum += s0; sumsq = fmaf(s0, s0, sumsq);
        sum += s1; sumsq = fmaf(s1, s1, sumsq);
        sum += s2; sumsq = fmaf(s2, s2, sumsq);
        sum += s3; sumsq = fmaf(s3, s3, sumsq);
    }
    red[0][slot][l] = sum;
    red[1][slot][l] = sumsq;
    __syncthreads();
    if (t < FT) {
        float v = red[0][0][t] + red[0][1][t] + red[0][2][t] + red[0][3][t];
        ws[OFF_PS + (ft * RB + rb) * FT + t] = v;
    } else if (t < 2 * FT) {
        int u = t - FT;
        float v = red[1][0][u] + red[1][1][u] + red[1][2][u] + red[1][3][u];
        ws[OFF_PS2 + (ft * RB + rb) * FT + u] = v;
    }
}

__global__ __launch_bounds__(256) void k_reduce(float* __restrict__ ws) {
    int f = blockIdx.x;
    int ft = f >> 6, l = f & 63;
    int t = threadIdx.x;
    __shared__ float r1[256], r2[256];
    r1[t] = ws[OFF_PS + (ft * RB + t) * FT + l];
    r2[t] = ws[OFF_PS2 + (ft * RB + t) * FT + l];
    __syncthreads();
    for (int off = 128; off > 0; off >>= 1) {
        if (t < off) { r1[t] += r1[t + off]; r2[t] += r2[t + off]; }
        __syncthreads();
    }
    if (t == 0) {
        float mean = r1[0] * (1.0f / (float)BATCH);
        float var = r2[0] * (1.0f / (float)BATCH) - mean * mean;
        var = fmaxf(var, 0.0f);
        ws[OFF_MEAN + f] = mean;
        ws[OFF_ISTD + f] = 1.0f / sqrtf(var + EPSF);
    }
}

__global__ __launch_bounds__(256, 4) void k_pass2(const float* __restrict__ X,
                                                  const float* __restrict__ shiftp,
                                                  const float* __restrict__ scalep,
                                                  const float* __restrict__ ws,
                                                  float* __restrict__ Z) {
    __shared__ float4 sP0[FT * 17];
    __shared__ float4 sP1[FT * 17];
    int t = threadIdx.x;
    int rb = blockIdx.x, ft = blockIdx.y;
    const float4* P0g = (const float4*)(ws + OFF_P0) + ft * FT * 17;
    const float4* P1g = (const float4*)(ws + OFF_P1) + ft * FT * 17;
    for (int i = t; i < FT * 17; i += 256) { sP0[i] = P0g[i]; sP1[i] = P1g[i]; }
    int l = t & 63, slot = t >> 6;
    int f = ft * FT + l;
    float kn[15];
#pragma unroll
    for (int j = 0; j < 15; j++) kn[j] = ws[OFF_CW + f * 17 + 1 + j];
    float a = 1.0f / scalep[f];
    float nb = -shiftp[f] * a;
    float mean = ws[OFF_MEAN + f];
    float istd = ws[OFF_ISTD + f];
    int l17 = l * 17;
    __syncthreads();
    size_t base = (size_t)(rb * ROWS_PB + slot) * FEAT + f;
    const float* Xp = X + base;
    float* Zp = Z + base;
    for (int r = 0; r < ITERS; r += 4) {
        float x0 = Xp[0 * SLOTS * FEAT];
        float x1 = Xp[1 * SLOTS * FEAT];
        float x2 = Xp[2 * SLOTS * FEAT];
        float x3 = Xp[3 * SLOTS * FEAT];
        Xp += 4 * SLOTS * FEAT;
        float s0 = eval_rq(x0, a, nb, sP0, sP1, kn, l17);
        float s1 = eval_rq(x1, a, nb, sP0, sP1, kn, l17);
        float s2 = eval_rq(x2, a, nb, sP0, sP1, kn, l17);
        float s3 = eval_rq(x3, a, nb, sP0, sP1, kn, l17);
        Zp[0 * SLOTS * FEAT] = (s0 - mean) * istd;
        Zp[1 * SLOTS * FEAT] = (s1 - mean) * istd;
        Zp[2 * SLOTS * FEAT] = (s2 - mean) * istd;
        Zp[3 * SLOTS * FEAT] = (s3 - mean) * istd;
        Zp += 4 * SLOTS * FEAT;
    }
}

extern "C" void kernel_launch(void* const* d_in, const int* in_sizes, int n_in,
                              void* d_out, int out_size, void* d_ws, size_t ws_size,
                              hipStream_t stream) {
    const float* x     = (const float*)d_in[0];
    const float* uw    = (const float*)d_in[1];
    const float* uh    = (const float*)d_in[2];
    const float* ud    = (const float*)d_in[3];
    const float* shift = (const float*)d_in[4];
    const float* scale = (const float*)d_in[5];
    float* out = (float*)d_out;
    float* ws  = (float*)d_ws;

    k_params<<<1, 256, 0, stream>>>(uw, uh, ud, ws);
    k_pass1<<<dim3(RB, FT_TILES), 256, 0, stream>>>(x, shift, scale, ws);
    k_reduce<<<FEAT, 256, 0, stream>>>(ws);
    k_pass2<<<dim3(RB, FT_TILES), 256, 0, stream>>>(x, shift, scale, ws, out);
}

// Round 3
// 114.262 us; speedup vs baseline: 1.3179x; 1.0225x over previous
//
#include <hip/hip_runtime.h>
#include <math.h>

// MonotoneFeatureTransform: rational-quadratic spline per feature + batch standardize.
// B=131072, F=256, K=16. f32 in/out.
// Strategy: pass1 evaluates spline ONCE, accumulates per-feature stats, stores s as
// bf16 in ws (if ws is big enough); pass2 is a pure streaming standardize.
// Fallback (small ws): recompute spline in pass2 (round-2 scheme).

#define FEAT 256
#define KBINS 16
#define BATCH 131072
#define BOUNDF 5.0f
#define MIN_Df 1e-3f
#define MIN_BWf 1e-3f
#define MIN_BHf 1e-3f
#define EPSF 1e-8f

#define FTB 32                 // features per tile
#define FT_TILES 8
#define SLOTB 8                // row slots per block (256 thr / 32 feat)
#define RBB 256                // row-blocks
#define ROWS_PB (BATCH / RBB)  // 512 rows per block
#define ITERB (ROWS_PB / SLOTB) // 64 rows per thread

// Table region, float offsets RELATIVE to `tab` pointer (~683 KB total)
#define R_P0   0                    // [256][17] float4: cw0*binv, binv, h*delta, h*d0
#define R_P1   17408                // [256][17] float4: dsum, delta, ch0, pad
#define R_CW   34816                // [256][17] knot x positions
#define R_MEAN 39168                // [256]
#define R_ISTD 39424                // [256]
#define R_PS   39680                // [2048][32] partial sums
#define R_PS2  (R_PS + 2048 * 32)   // [2048][32] partial sumsq
#define TAB_FLOATS (R_PS2 + 2048 * 32)   // 170752 floats
#define S_ELEMS ((size_t)BATCH * FEAT)   // bf16 elements
#define S_FLOATS (S_ELEMS / 2)           // 16777216 floats of ws used by S

__device__ __forceinline__ unsigned short f2bf(float x) {
    unsigned int b = __float_as_uint(x);
    unsigned int r = (b + 0x7fffu + ((b >> 16) & 1u)) >> 16;
    return (unsigned short)r;
}

__global__ __launch_bounds__(256) void k_params(const float* __restrict__ uw,
                                                const float* __restrict__ uh,
                                                const float* __restrict__ ud,
                                                float* __restrict__ tab) {
    int f = threadIdx.x;
    float cw[17], ch[17], dv[17];
    {
        float u[KBINS];
#pragma unroll
        for (int j = 0; j < KBINS; j++) u[j] = uw[f * KBINS + j];
        float m = u[0];
#pragma unroll
        for (int j = 1; j < KBINS; j++) m = fmaxf(m, u[j]);
        float ssum = 0.f;
#pragma unroll
        for (int j = 0; j < KBINS; j++) { u[j] = expf(u[j] - m); ssum += u[j]; }
        float inv = 1.0f / ssum;
        float cum = 0.f;
        cw[0] = -BOUNDF;
#pragma unroll
        for (int j = 1; j < KBINS; j++) {
            float wj = MIN_BWf + (1.0f - MIN_BWf * (float)KBINS) * (u[j - 1] * inv);
            cum += wj;
            cw[j] = 2.0f * BOUNDF * cum - BOUNDF;
        }
        cw[KBINS] = BOUNDF;
    }
    {
        float u[KBINS];
#pragma unroll
        for (int j = 0; j < KBINS; j++) u[j] = uh[f * KBINS + j];
        float m = u[0];
#pragma unroll
        for (int j = 1; j < KBINS; j++) m = fmaxf(m, u[j]);
        float ssum = 0.f;
#pragma unroll
        for (int j = 0; j < KBINS; j++) { u[j] = expf(u[j] - m); ssum += u[j]; }
        float inv = 1.0f / ssum;
        float cum = 0.f;
        ch[0] = -BOUNDF;
#pragma unroll
        for (int j = 1; j < KBINS; j++) {
            float wj = MIN_BHf + (1.0f - MIN_BHf * (float)KBINS) * (u[j - 1] * inv);
            cum += wj;
            ch[j] = 2.0f * BOUNDF * cum - BOUNDF;
        }
        ch[KBINS] = BOUNDF;
    }
    {
        dv[0] = 1.0f;
        dv[KBINS] = 1.0f;
#pragma unroll
        for (int j = 1; j < KBINS; j++) {
            float v = ud[f * (KBINS - 1) + (j - 1)];
            float sp = fmaxf(v, 0.0f) + log1pf(expf(-fabsf(v))); // stable softplus
            dv[j] = MIN_Df + sp;
        }
    }
#pragma unroll
    for (int j = 0; j <= KBINS; j++) tab[R_CW + f * 17 + j] = cw[j];
    float4* P0g = (float4*)(tab + R_P0);
    float4* P1g = (float4*)(tab + R_P1);
#pragma unroll
    for (int i = 0; i < KBINS; i++) {
        float w = cw[i + 1] - cw[i];
        float binv = 1.0f / w;
        float hb = ch[i + 1] - ch[i];
        float delta = hb * binv;
        float4 p0, p1;
        p0.x = cw[i] * binv;
        p0.y = binv;
        p0.z = hb * delta;
        p0.w = hb * dv[i];
        p1.x = dv[i] + dv[i + 1] - 2.0f * delta;
        p1.y = delta;
        p1.z = ch[i];
        p1.w = 0.0f;
        P0g[f * 17 + i] = p0;
        P1g[f * 17 + i] = p1;
    }
}

__device__ __forceinline__ float eval_rq(float xv, float a, float nb,
                                         const float4* __restrict__ sP0,
                                         const float4* __restrict__ sP1,
                                         const float kn[15], int l17) {
    float xn = fmaf(xv, a, nb);
    float xc = fminf(fmaxf(xn, -BOUNDF), BOUNDF);
    int idx = 0;
#pragma unroll
    for (int j = 0; j < 15; j++) idx += (xc >= kn[j]) ? 1 : 0;
    int o = l17 + idx;
    float4 p0 = sP0[o];
    float4 p1 = sP1[o];
    float th = fmaf(xc, p0.y, -p0.x);
    float th2 = th * th;
    float t1m = th - th2;
    float numer = fmaf(p0.z, th2, p0.w * t1m);
    float denom = fmaf(p1.x, t1m, p1.y);
    float s = fmaf(numer, __builtin_amdgcn_rcpf(denom), p1.z);
    return (fabsf(xn) < BOUNDF) ? s : xn;
}

template <bool STORE_S>
__global__ __launch_bounds__(256, 6) void k_pass1(const float* __restrict__ X,
                                                  const float* __restrict__ shiftp,
                                                  const float* __restrict__ scalep,
                                                  float* __restrict__ tab,
                                                  unsigned short* __restrict__ S) {
    __shared__ float4 sP0[FTB * 17];
    __shared__ float4 sP1[FTB * 17];
    __shared__ float red[2][SLOTB][FTB];
    int t = threadIdx.x;
    int rb = blockIdx.x, ft = blockIdx.y;
    const float4* P0g = (const float4*)(tab + R_P0) + ft * FTB * 17;
    const float4* P1g = (const float4*)(tab + R_P1) + ft * FTB * 17;
    for (int i = t; i < FTB * 17; i += 256) { sP0[i] = P0g[i]; sP1[i] = P1g[i]; }
    int l = t & 31, slot = t >> 5;
    int f = ft * FTB + l;
    float kn[15];
#pragma unroll
    for (int j = 0; j < 15; j++) kn[j] = tab[R_CW + f * 17 + 1 + j];
    float a = 1.0f / scalep[f];
    float nb = -shiftp[f] * a;
    int l17 = l * 17;
    __syncthreads();
    size_t base = (size_t)(rb * ROWS_PB + slot) * FEAT + f;
    const float* Xp = X + base;
    unsigned short* Sp = STORE_S ? (S + base) : nullptr;
    float sum = 0.f, sumsq = 0.f;
    for (int r = 0; r < ITERB; r += 4) {
        float x0 = Xp[0 * SLOTB * FEAT];
        float x1 = Xp[1 * SLOTB * FEAT];
        float x2 = Xp[2 * SLOTB * FEAT];
        float x3 = Xp[3 * SLOTB * FEAT];
        Xp += 4 * SLOTB * FEAT;
        float s0 = eval_rq(x0, a, nb, sP0, sP1, kn, l17);
        float s1 = eval_rq(x1, a, nb, sP0, sP1, kn, l17);
        float s2 = eval_rq(x2, a, nb, sP0, sP1, kn, l17);
        float s3 = eval_rq(x3, a, nb, sP0, sP1, kn, l17);
        if (STORE_S) {
            Sp[0 * SLOTB * FEAT] = f2bf(s0);
            Sp[1 * SLOTB * FEAT] = f2bf(s1);
            Sp[2 * SLOTB * FEAT] = f2bf(s2);
            Sp[3 * SLOTB * FEAT] = f2bf(s3);
            Sp += 4 * SLOTB * FEAT;
        }
        sum += s0; sumsq = fmaf(s0, s0, sumsq);
        sum += s1; sumsq = fmaf(s1, s1, sumsq);
        sum += s2; sumsq = fmaf(s2, s2, sumsq);
        sum += s3; sumsq = fmaf(s3, s3, sumsq);
    }
    red[0][slot][l] = sum;
    red[1][slot][l] = sumsq;
    __syncthreads();
    if (t < FTB) {
        float v = 0.f;
#pragma unroll
        for (int s2i = 0; s2i < SLOTB; s2i++) v += red[0][s2i][t];
        tab[R_PS + (ft * RBB + rb) * FTB + t] = v;
    } else if (t < 2 * FTB) {
        int u = t - FTB;
        float v = 0.f;
#pragma unroll
        for (int s2i = 0; s2i < SLOTB; s2i++) v += red[1][s2i][u];
        tab[R_PS2 + (ft * RBB + rb) * FTB + u] = v;
    }
}

__global__ __launch_bounds__(256) void k_reduce(float* __restrict__ tab) {
    int f = blockIdx.x;
    int ft = f >> 5, l = f & 31;
    int t = threadIdx.x;
    __shared__ float r1[256], r2[256];
    r1[t] = tab[R_PS + (ft * RBB + t) * FTB + l];
    r2[t] = tab[R_PS2 + (ft * RBB + t) * FTB + l];
    __syncthreads();
    for (int off = 128; off > 0; off >>= 1) {
        if (t < off) { r1[t] += r1[t + off]; r2[t] += r2[t + off]; }
        __syncthreads();
    }
    if (t == 0) {
        float mean = r1[0] * (1.0f / (float)BATCH);
        float var = r2[0] * (1.0f / (float)BATCH) - mean * mean;
        var = fmaxf(var, 0.0f);
        tab[R_MEAN + f] = mean;
        tab[R_ISTD + f] = 1.0f / sqrtf(var + EPSF);
    }
}

// Streaming standardize: z = s*istd - mean*istd, s from bf16 buffer.
__global__ __launch_bounds__(256, 8) void k_pass2_stream(const unsigned short* __restrict__ S,
                                                         const float* __restrict__ tab,
                                                         float* __restrict__ Z) {
    int gid = blockIdx.x * 256 + threadIdx.x;   // 524288 threads
    int fg = gid & 31;                          // feature-group: features fg*8 .. fg*8+7
    int rs = gid >> 5;                          // row-slot: rows rs*8 .. rs*8+7
    const float* meanp = tab + R_MEAN + fg * 8;
    const float* istdp = tab + R_ISTD + fg * 8;
    float istd[8], nmi[8];
#pragma unroll
    for (int j = 0; j < 8; j++) {
        float m = meanp[j];
        float is = istdp[j];
        istd[j] = is;
        nmi[j] = -m * is;
    }
    size_t idx = (size_t)rs * 8 * FEAT + fg * 8;
#pragma unroll
    for (int r = 0; r < 8; r++) {
        uint4 sv = *(const uint4*)(S + idx);
        float z0 = fmaf(__uint_as_float((sv.x & 0xffffu) << 16), istd[0], nmi[0]);
        float z1 = fmaf(__uint_as_float(sv.x & 0xffff0000u),     istd[1], nmi[1]);
        float z2 = fmaf(__uint_as_float((sv.y & 0xffffu) << 16), istd[2], nmi[2]);
        float z3 = fmaf(__uint_as_float(sv.y & 0xffff0000u),     istd[3], nmi[3]);
        float z4 = fmaf(__uint_as_float((sv.z & 0xffffu) << 16), istd[4], nmi[4]);
        float z5 = fmaf(__uint_as_float(sv.z & 0xffff0000u),     istd[5], nmi[5]);
        float z6 = fmaf(__uint_as_float((sv.w & 0xffffu) << 16), istd[6], nmi[6]);
        float z7 = fmaf(__uint_as_float(sv.w & 0xffff0000u),     istd[7], nmi[7]);
        float4* Zp = (float4*)(Z + idx);
        Zp[0] = make_float4(z0, z1, z2, z3);
        Zp[1] = make_float4(z4, z5, z6, z7);
        idx += FEAT;
    }
}

// Fallback pass2: recompute spline (when ws can't hold S).
__global__ __launch_bounds__(256, 6) void k_pass2_eval(const float* __restrict__ X,
                                                       const float* __restrict__ shiftp,
                                                       const float* __restrict__ scalep,
                                                       const float* __restrict__ tab,
                                                       float* __restrict__ Z) {
    __shared__ float4 sP0[FTB * 17];
    __shared__ float4 sP1[FTB * 17];
    int t = threadIdx.x;
    int rb = blockIdx.x, ft = blockIdx.y;
    const float4* P0g = (const float4*)(tab + R_P0) + ft * FTB * 17;
    const float4* P1g = (const float4*)(tab + R_P1) + ft * FTB * 17;
    for (int i = t; i < FTB * 17; i += 256) { sP0[i] = P0g[i]; sP1[i] = P1g[i]; }
    int l = t & 31, slot = t >> 5;
    int f = ft * FTB + l;
    float kn[15];
#pragma unroll
    for (int j = 0; j < 15; j++) kn[j] = tab[R_CW + f * 17 + 1 + j];
    float a = 1.0f / scalep[f];
    float nb = -shiftp[f] * a;
    float mean = tab[R_MEAN + f];
    float istd = tab[R_ISTD + f];
    int l17 = l * 17;
    __syncthreads();
    size_t base = (size_t)(rb * ROWS_PB + slot) * FEAT + f;
    const float* Xp = X + base;
    float* Zp = Z + base;
    for (int r = 0; r < ITERB; r += 4) {
        float x0 = Xp[0 * SLOTB * FEAT];
        float x1 = Xp[1 * SLOTB * FEAT];
        float x2 = Xp[2 * SLOTB * FEAT];
        float x3 = Xp[3 * SLOTB * FEAT];
        Xp += 4 * SLOTB * FEAT;
        float s0 = eval_rq(x0, a, nb, sP0, sP1, kn, l17);
        float s1 = eval_rq(x1, a, nb, sP0, sP1, kn, l17);
        float s2 = eval_rq(x2, a, nb, sP0, sP1, kn, l17);
        float s3 = eval_rq(x3, a, nb, sP0, sP1, kn, l17);
        Zp[0 * SLOTB * FEAT] = (s0 - mean) * istd;
        Zp[1 * SLOTB * FEAT] = (s1 - mean) * istd;
        Zp[2 * SLOTB * FEAT] = (s2 - mean) * istd;
        Zp[3 * SLOTB * FEAT] = (s3 - mean) * istd;
        Zp += 4 * SLOTB * FEAT;
    }
}

extern "C" void kernel_launch(void* const* d_in, const int* in_sizes, int n_in,
                              void* d_out, int out_size, void* d_ws, size_t ws_size,
                              hipStream_t stream) {
    const float* x     = (const float*)d_in[0];
    const float* uw    = (const float*)d_in[1];
    const float* uh    = (const float*)d_in[2];
    const float* ud    = (const float*)d_in[3];
    const float* shift = (const float*)d_in[4];
    const float* scale = (const float*)d_in[5];
    float* out = (float*)d_out;
    float* ws  = (float*)d_ws;

    size_t need = (S_FLOATS + (size_t)TAB_FLOATS) * sizeof(float);
    bool useS = ws_size >= need;
    float* tab = ws + (useS ? S_FLOATS : 0);
    unsigned short* S = (unsigned short*)ws;

    k_params<<<1, 256, 0, stream>>>(uw, uh, ud, tab);
    if (useS) {
        k_pass1<true><<<dim3(RBB, FT_TILES), 256, 0, stream>>>(x, shift, scale, tab, S);
        k_reduce<<<FEAT, 256, 0, stream>>>(tab);
        k_pass2_stream<<<2048, 256, 0, stream>>>(S, tab, out);
    } else {
        k_pass1<false><<<dim3(RBB, FT_TILES), 256, 0, stream>>>(x, shift, scale, tab, nullptr);
        k_reduce<<<FEAT, 256, 0, stream>>>(tab);
        k_pass2_eval<<<dim3(RBB, FT_TILES), 256, 0, stream>>>(x, shift, scale, tab, out);
    }
}